// Round 12
// baseline (61.095 us; speedup 1.0000x reference)
//
#include <hip/hip_runtime.h>
#include <cmath>

#define T_SEQ 4096
#define D_MODEL 1024
#define EPS 1e-6f
#define CHUNKS 16   // ctx: grid 256 = 1 block/CU
#define RSTRIDE 257 // f32 row stride in LDS: 1-dword pad -> column gathers ~2-way/bank

typedef __attribute__((ext_vector_type(8))) short bf16x8;
typedef __attribute__((ext_vector_type(4))) float f32x4;

__device__ __forceinline__ float elu1(float x) { return x > 0.f ? x + 1.f : __expf(x); }

// float -> bf16 bits, round-to-nearest-even
__device__ __forceinline__ unsigned f2bf_u(float f) {
    union { float f; unsigned u; } v; v.f = f;
    unsigned r = v.u + 0x7fffu + ((v.u >> 16) & 1u);
    return r >> 16;
}
__device__ __forceinline__ short f2bf(float f) { return (short)f2bf_u(f); }
// pack 2 f32 -> 2 bf16 (RNE), dst.lo = first arg (proven R5-R11)
__device__ __forceinline__ unsigned cvt_pk_bf16(float lo, float hi) {
    unsigned r;
    asm("v_cvt_pk_bf16_f32 %0, %1, %2" : "=v"(r) : "v"(lo), "v"(hi));
    return r;
}
__device__ __forceinline__ float bf2f(unsigned short s) {
    union { unsigned u; float f; } v; v.u = ((unsigned)s) << 16;
    return v.f;
}

// ---------------------------------------------------------------------------
// Kernel A: fused 4-head partial-context blocks, global_load_lds staging.
// (R11-verbatim machinery; slab output now bf16 via cvt_pk -> half traffic.)
// grid = 256 (4 b x 4 head-quads x 16 chunks), 1024 threads (16 waves).
// ---------------------------------------------------------------------------
__global__ __launch_bounds__(1024) void ctx_fused(const float* __restrict__ K,
                                                  const float* __restrict__ V,
                                                  unsigned short* __restrict__ partial) {
    __shared__ __align__(16) float sL[2][2][32 * RSTRIDE];  // [buf][K=0,V=1][row*257+col]

    const int bb = blockIdx.x >> 6;
    const int hq = (blockIdx.x >> 4) & 3;
    const int ch = blockIdx.x & 15;
    const int tid = threadIdx.x;
    const int wave = tid >> 6, lane = tid & 63;
    const int hh = wave >> 2, qd = wave & 3, eh = qd >> 1, dh = qd & 1;
    const int g = lane >> 4, r = lane & 15;
    const int u = wave;                 // staging: wave u owns rows 2u, 2u+1

    const size_t base = (size_t)bb * T_SEQ * D_MODEL;
    const int s0 = ch * 256;
    const int colb = hq * 256;

    f32x4 acc[2][2], accs[2];
#pragma unroll
    for (int i = 0; i < 2; ++i)
#pragma unroll
        for (int q = 0; q < 4; ++q) { accs[i][q] = 0.f; acc[i][0][q] = 0.f; acc[i][1][q] = 0.f; }

    bf16x8 ones;
    const short ob = (r == 0) ? (short)0x3F80 : (short)0;
#pragma unroll
    for (int j = 0; j < 8; ++j) ones[j] = ob;

    union U8 { unsigned u[4]; bf16x8 v; };

    auto stage = [&](int t, int buf) {
        const size_t gr = base + (size_t)(s0 + 32 * t + 2 * u) * D_MODEL + colb + 4 * lane;
        const float* Kp = K + gr;
        const float* Vp = V + gr;
        float* dK = &sL[buf][0][(2 * u) * RSTRIDE];
        float* dV = &sL[buf][1][(2 * u) * RSTRIDE];
        __builtin_amdgcn_global_load_lds((const unsigned*)Kp, (unsigned*)dK, 16, 0, 0);
        __builtin_amdgcn_global_load_lds((const unsigned*)(Kp + D_MODEL),
                                         (unsigned*)(dK + RSTRIDE), 16, 0, 0);
        __builtin_amdgcn_global_load_lds((const unsigned*)Vp, (unsigned*)dV, 16, 0, 0);
        __builtin_amdgcn_global_load_lds((const unsigned*)(Vp + D_MODEL),
                                         (unsigned*)(dV + RSTRIDE), 16, 0, 0);
    };

    auto compute = [&](int buf) {
        const float* tk = &sL[buf][0][0];
        const float* tv = &sL[buf][1][0];
        const int hb = hh * 64;
        bf16x8 a[2], bv[2];
#pragma unroll
        for (int mi = 0; mi < 2; ++mi) {
            const int col = hb + 32 * eh + 16 * mi + r;
            float f[8];
#pragma unroll
            for (int j = 0; j < 8; ++j) f[j] = tk[(8 * g + j) * RSTRIDE + col];
            U8 t;
            t.u[0] = cvt_pk_bf16(elu1(f[0]), elu1(f[1]));
            t.u[1] = cvt_pk_bf16(elu1(f[2]), elu1(f[3]));
            t.u[2] = cvt_pk_bf16(elu1(f[4]), elu1(f[5]));
            t.u[3] = cvt_pk_bf16(elu1(f[6]), elu1(f[7]));
            a[mi] = t.v;
        }
#pragma unroll
        for (int ni = 0; ni < 2; ++ni) {
            const int col = hb + 32 * dh + 16 * ni + r;
            float f[8];
#pragma unroll
            for (int j = 0; j < 8; ++j) f[j] = tv[(8 * g + j) * RSTRIDE + col];
            U8 t;
            t.u[0] = cvt_pk_bf16(f[0], f[1]);
            t.u[1] = cvt_pk_bf16(f[2], f[3]);
            t.u[2] = cvt_pk_bf16(f[4], f[5]);
            t.u[3] = cvt_pk_bf16(f[6], f[7]);
            bv[ni] = t.v;
        }
#pragma unroll
        for (int mi = 0; mi < 2; ++mi) {
#pragma unroll
            for (int ni = 0; ni < 2; ++ni)
                acc[mi][ni] = __builtin_amdgcn_mfma_f32_16x16x32_bf16(a[mi], bv[ni], acc[mi][ni], 0, 0, 0);
            if (dh == 0)
                accs[mi] = __builtin_amdgcn_mfma_f32_16x16x32_bf16(a[mi], ones, accs[mi], 0, 0, 0);
        }
    };

    stage(0, 0);
    __syncthreads();
#pragma unroll 1
    for (int t = 0; t < 8; ++t) {
        if (t < 7) stage(t + 1, (t + 1) & 1);
        compute(t & 1);
        __syncthreads();
    }

    // bf16 slab: [qd][t2][lane][4] shorts + ksum tail (e-order)
    unsigned short* slab = partial + ((size_t)((bb * 16 + hq * 4 + hh) * CHUNKS + ch)) * 4160;
#pragma unroll
    for (int mi = 0; mi < 2; ++mi)
#pragma unroll
        for (int ni = 0; ni < 2; ++ni) {
            uint2 w;
            w.x = cvt_pk_bf16(acc[mi][ni][0], acc[mi][ni][1]);
            w.y = cvt_pk_bf16(acc[mi][ni][2], acc[mi][ni][3]);
            *(uint2*)&slab[qd * 1024 + (mi * 2 + ni) * 256 + lane * 4] = w;
        }
    if (dh == 0 && r == 0) {
#pragma unroll
        for (int mi = 0; mi < 2; ++mi) {
            uint2 w;
            w.x = cvt_pk_bf16(accs[mi][0], accs[mi][1]);
            w.y = cvt_pk_bf16(accs[mi][2], accs[mi][3]);
            *(uint2*)&slab[4096 + 32 * eh + 16 * mi + 4 * g] = w;
        }
    }
}

// ---------------------------------------------------------------------------
// Kernel A2: sum 16 bf16 chunk blobs -> TRANSPOSED bf16 context (frag-ready).
// CT[d][e] = bf16(ctx[e][d]); CT[64][e] = bf16(ksum[e]). grid = 256.
// ---------------------------------------------------------------------------
__global__ __launch_bounds__(256) void ctx_reduce(const unsigned short* __restrict__ partial,
                                                  unsigned short* __restrict__ ctxbf) {
    const int head = blockIdx.x >> 2, part = blockIdx.x & 3;
    const unsigned short* pbase = partial + (size_t)head * CHUNKS * 4160;
    unsigned short* cbase = ctxbf + (size_t)head * 4160;
    const int lo = part * 260;
    for (int i4 = lo + threadIdx.x; i4 < lo + 260; i4 += 256) {
        float s[4] = {0.f, 0.f, 0.f, 0.f};
#pragma unroll
        for (int c = 0; c < CHUNKS; ++c) {
            const ushort4 v = *(const ushort4*)&pbase[(size_t)c * 4160 + i4 * 4];
            s[0] += bf2f(v.x); s[1] += bf2f(v.y);
            s[2] += bf2f(v.z); s[3] += bf2f(v.w);
        }
        const int f0 = i4 * 4;
        if (f0 < 4096) {
#pragma unroll
            for (int k = 0; k < 4; ++k) {
                const int f = f0 + k;
                const int qd = f >> 10, t2 = (f >> 8) & 3, ln = (f >> 2) & 63, q = f & 3;
                const int e = 32 * (qd >> 1) + 16 * (t2 >> 1) + 4 * (ln >> 4) + q;
                const int d = 32 * (qd & 1) + 16 * (t2 & 1) + (ln & 15);
                cbase[d * 64 + e] = (unsigned short)f2bf(s[k]);
            }
        } else {
#pragma unroll
            for (int k = 0; k < 4; ++k) cbase[f0 + k] = (unsigned short)f2bf(s[k]);
        }
    }
}

// ---------------------------------------------------------------------------
// Kernel B: fused 4-head attn_out with global_load_lds Q staging.
// grid = 256 (4 b x 4 head-quads x 16 row-chunks), 1024 threads (16 waves).
// Q staged as dense 1-KB rows -> [64][257] f32 LDS, double-buffered (131.6KB).
// Rows are independent (no cross-tile reduction): per 64-row tile, wave
// (hh, mp) computes output rows 16*mp..+16 of head hh: A-frags = 2x
// ds_read_b128 per kt + elu/cvt_pk; 10 MFMA; shfl-dinv; scalar stores.
// B-frags (frag-ready CT, proven R8 layout) loaded once per wave.
// ---------------------------------------------------------------------------
__global__ __launch_bounds__(1024) void attn_fused(const float* __restrict__ Q,
                                                   const unsigned short* __restrict__ ctxbf,
                                                   float* __restrict__ out) {
    __shared__ __align__(16) float sQ[2][64 * RSTRIDE];

    const int bb = blockIdx.x >> 6;
    const int hq = (blockIdx.x >> 4) & 3;
    const int ch = blockIdx.x & 15;
    const int tid = threadIdx.x;
    const int wave = tid >> 6, lane = tid & 63;
    const int hh = wave >> 2, mp = wave & 3;
    const int g = lane >> 4, r = lane & 15;
    const int u = wave;                 // staging: wave u owns tile rows 4u..4u+3

    const int head = bb * 16 + hq * 4 + hh;
    const size_t qb = (size_t)bb * T_SEQ * D_MODEL;
    const int n0 = ch * 256;
    const int colb = hq * 256;

    // B-frags for head hh (frag-ready CT; R8-proven layout)
    const unsigned short* C = ctxbf + (size_t)head * 4160;
    bf16x8 bfr[2][5];
#pragma unroll
    for (int kt = 0; kt < 2; ++kt) {
#pragma unroll
        for (int n = 0; n < 4; ++n)
            bfr[kt][n] = *(const bf16x8*)&C[(16 * n + r) * 64 + kt * 32 + 8 * g];
        bf16x8 ks = *(const bf16x8*)&C[4096 + kt * 32 + 8 * g];
        if (r != 0) {
#pragma unroll
            for (int j = 0; j < 8; ++j) ks[j] = 0;
        }
        bfr[kt][4] = ks;
    }

    union U8 { unsigned u[4]; bf16x8 v; };

    auto stage = [&](int tl, int buf) {
        const float* Qp = Q + qb + (size_t)(n0 + 64 * tl + 4 * u) * D_MODEL + colb + 4 * lane;
        float* dst = &sQ[buf][(4 * u) * RSTRIDE];
#pragma unroll
        for (int i = 0; i < 4; ++i)
            __builtin_amdgcn_global_load_lds((const unsigned*)(Qp + (size_t)i * D_MODEL),
                                             (unsigned*)(dst + i * RSTRIDE), 16, 0, 0);
    };

    auto compute = [&](int tl, int buf) {
        const float* tq = &sQ[buf][0];
        f32x4 acc[5];
#pragma unroll
        for (int n = 0; n < 5; ++n)
#pragma unroll
            for (int q = 0; q < 4; ++q) acc[n][q] = 0.f;

#pragma unroll
        for (int kt = 0; kt < 2; ++kt) {
            const float* p = &tq[(16 * mp + r) * RSTRIDE + hh * 64 + kt * 32 + 8 * g];
            float f[8];
#pragma unroll
            for (int j = 0; j < 8; ++j) f[j] = p[j];
            U8 a;
            a.u[0] = cvt_pk_bf16(elu1(f[0]), elu1(f[1]));
            a.u[1] = cvt_pk_bf16(elu1(f[2]), elu1(f[3]));
            a.u[2] = cvt_pk_bf16(elu1(f[4]), elu1(f[5]));
            a.u[3] = cvt_pk_bf16(elu1(f[6]), elu1(f[7]));
#pragma unroll
            for (int n = 0; n < 5; ++n)
                acc[n] = __builtin_amdgcn_mfma_f32_16x16x32_bf16(a.v, bfr[kt][n], acc[n], 0, 0, 0);
        }

        float dinv[4];
#pragma unroll
        for (int q = 0; q < 4; ++q)
            dinv[q] = 1.f / (__shfl(acc[4][q], lane & 48) + EPS);
        const int rowb = n0 + 64 * tl + 16 * mp;
#pragma unroll
        for (int q = 0; q < 4; ++q) {
            float* op = out + ((size_t)bb * T_SEQ + rowb + 4 * g + q) * D_MODEL
                        + (size_t)(hq * 4 + hh) * 64 + r;
#pragma unroll
            for (int n = 0; n < 4; ++n) op[16 * n] = acc[n][q] * dinv[q];
        }
    };

    stage(0, 0);
    __syncthreads();
#pragma unroll 1
    for (int tl = 0; tl < 4; ++tl) {
        if (tl < 3) stage(tl + 1, (tl + 1) & 1);
        compute(tl, tl & 1);
        __syncthreads();
    }
}

extern "C" void kernel_launch(void* const* d_in, const int* in_sizes, int n_in,
                              void* d_out, int out_size, void* d_ws, size_t ws_size,
                              hipStream_t stream) {
    const float* Q = (const float*)d_in[0];
    const float* K = (const float*)d_in[1];
    const float* V = (const float*)d_in[2];
    float* out = (float*)d_out;

    // Partials (1024 slabs * 4160 bf16 = 8.5 MB) live in d_out-as-scratch;
    // consumed by ctx_reduce, then d_out is fully overwritten by attn_fused.
    unsigned short* partial = (unsigned short*)d_out;
    unsigned short* ctxbf   = (unsigned short*)d_ws;   // 64*4160 shorts (~0.5 MB)

    hipLaunchKernelGGL(ctx_fused,  dim3(256), dim3(1024), 0, stream, K, V, partial);
    hipLaunchKernelGGL(ctx_reduce, dim3(256), dim3(256),  0, stream, partial, ctxbf);
    hipLaunchKernelGGL(attn_fused, dim3(256), dim3(1024), 0, stream, Q, ctxbf, out);
}

// Round 13
// 56.726 us; speedup vs baseline: 1.0770x; 1.0770x over previous
//
#include <hip/hip_runtime.h>
#include <cmath>

#define T_SEQ 4096
#define D_MODEL 1024
#define EPS 1e-6f
#define CHUNKS 16   // ctx: grid 256 = 1 block/CU
#define RSTRIDE 257 // f32 row stride in LDS: 1-dword pad -> column gathers ~2-way/bank

typedef __attribute__((ext_vector_type(8))) short bf16x8;
typedef __attribute__((ext_vector_type(4))) float f32x4;

__device__ __forceinline__ float elu1(float x) { return x > 0.f ? x + 1.f : __expf(x); }

// float -> bf16 bits, round-to-nearest-even
__device__ __forceinline__ unsigned f2bf_u(float f) {
    union { float f; unsigned u; } v; v.f = f;
    unsigned r = v.u + 0x7fffu + ((v.u >> 16) & 1u);
    return r >> 16;
}
__device__ __forceinline__ short f2bf(float f) { return (short)f2bf_u(f); }
// pack 2 f32 -> 2 bf16 (RNE), dst.lo = first arg (proven R5-R12)
__device__ __forceinline__ unsigned cvt_pk_bf16(float lo, float hi) {
    unsigned r;
    asm("v_cvt_pk_bf16_f32 %0, %1, %2" : "=v"(r) : "v"(lo), "v"(hi));
    return r;
}
__device__ __forceinline__ float bf2f(unsigned short s) {
    union { unsigned u; float f; } v; v.u = ((unsigned)s) << 16;
    return v.f;
}

// ---------------------------------------------------------------------------
// Kernel A: fused 4-head partial-context blocks, global_load_lds staging,
// counted-vmcnt pipeline (no vmcnt(0) drain in the main loop).
// grid = 256 (4 b x 4 head-quads x 16 chunks), 1024 threads (16 waves).
// Per step: stage(t+1) issues 4 gload_lds/wave into buf^1 (stays in flight
// across barriers) -> s_waitcnt vmcnt(4) (buf t landed; t+1 still flying) ->
// s_barrier (publish) -> compute(t) -> s_barrier (read-complete before
// overwrite). No other vmem ops in the loop, so vmcnt counts are exact.
// ---------------------------------------------------------------------------
__global__ __launch_bounds__(1024) void ctx_fused(const float* __restrict__ K,
                                                  const float* __restrict__ V,
                                                  unsigned short* __restrict__ partial) {
    __shared__ __align__(16) float sL[2][2][32 * RSTRIDE];  // [buf][K=0,V=1][row*257+col]

    const int bb = blockIdx.x >> 6;
    const int hq = (blockIdx.x >> 4) & 3;
    const int ch = blockIdx.x & 15;
    const int tid = threadIdx.x;
    const int wave = tid >> 6, lane = tid & 63;
    const int hh = wave >> 2, qd = wave & 3, eh = qd >> 1, dh = qd & 1;
    const int g = lane >> 4, r = lane & 15;
    const int u = wave;                 // staging: wave u owns rows 2u, 2u+1

    const size_t base = (size_t)bb * T_SEQ * D_MODEL;
    const int s0 = ch * 256;
    const int colb = hq * 256;

    f32x4 acc[2][2], accs[2];
#pragma unroll
    for (int i = 0; i < 2; ++i)
#pragma unroll
        for (int q = 0; q < 4; ++q) { accs[i][q] = 0.f; acc[i][0][q] = 0.f; acc[i][1][q] = 0.f; }

    bf16x8 ones;
    const short ob = (r == 0) ? (short)0x3F80 : (short)0;
#pragma unroll
    for (int j = 0; j < 8; ++j) ones[j] = ob;

    union U8 { unsigned u[4]; bf16x8 v; };

    auto stage = [&](int t, int buf) {
        const size_t gr = base + (size_t)(s0 + 32 * t + 2 * u) * D_MODEL + colb + 4 * lane;
        const float* Kp = K + gr;
        const float* Vp = V + gr;
        float* dK = &sL[buf][0][(2 * u) * RSTRIDE];
        float* dV = &sL[buf][1][(2 * u) * RSTRIDE];
        __builtin_amdgcn_global_load_lds((const unsigned*)Kp, (unsigned*)dK, 16, 0, 0);
        __builtin_amdgcn_global_load_lds((const unsigned*)(Kp + D_MODEL),
                                         (unsigned*)(dK + RSTRIDE), 16, 0, 0);
        __builtin_amdgcn_global_load_lds((const unsigned*)Vp, (unsigned*)dV, 16, 0, 0);
        __builtin_amdgcn_global_load_lds((const unsigned*)(Vp + D_MODEL),
                                         (unsigned*)(dV + RSTRIDE), 16, 0, 0);
    };

    auto compute = [&](int buf) {
        const float* tk = &sL[buf][0][0];
        const float* tv = &sL[buf][1][0];
        const int hb = hh * 64;
        bf16x8 a[2], bv[2];
#pragma unroll
        for (int mi = 0; mi < 2; ++mi) {
            const int col = hb + 32 * eh + 16 * mi + r;
            float f[8];
#pragma unroll
            for (int j = 0; j < 8; ++j) f[j] = tk[(8 * g + j) * RSTRIDE + col];
            U8 t;
            t.u[0] = cvt_pk_bf16(elu1(f[0]), elu1(f[1]));
            t.u[1] = cvt_pk_bf16(elu1(f[2]), elu1(f[3]));
            t.u[2] = cvt_pk_bf16(elu1(f[4]), elu1(f[5]));
            t.u[3] = cvt_pk_bf16(elu1(f[6]), elu1(f[7]));
            a[mi] = t.v;
        }
#pragma unroll
        for (int ni = 0; ni < 2; ++ni) {
            const int col = hb + 32 * dh + 16 * ni + r;
            float f[8];
#pragma unroll
            for (int j = 0; j < 8; ++j) f[j] = tv[(8 * g + j) * RSTRIDE + col];
            U8 t;
            t.u[0] = cvt_pk_bf16(f[0], f[1]);
            t.u[1] = cvt_pk_bf16(f[2], f[3]);
            t.u[2] = cvt_pk_bf16(f[4], f[5]);
            t.u[3] = cvt_pk_bf16(f[6], f[7]);
            bv[ni] = t.v;
        }
#pragma unroll
        for (int mi = 0; mi < 2; ++mi) {
#pragma unroll
            for (int ni = 0; ni < 2; ++ni)
                acc[mi][ni] = __builtin_amdgcn_mfma_f32_16x16x32_bf16(a[mi], bv[ni], acc[mi][ni], 0, 0, 0);
            if (dh == 0)
                accs[mi] = __builtin_amdgcn_mfma_f32_16x16x32_bf16(a[mi], ones, accs[mi], 0, 0, 0);
        }
    };

    stage(0, 0);
#pragma unroll 1
    for (int t = 0; t < 8; ++t) {
        if (t < 7) {
            stage(t + 1, (t + 1) & 1);
            asm volatile("s_waitcnt vmcnt(4)" ::: "memory");   // buf t landed; t+1 in flight
        } else {
            asm volatile("s_waitcnt vmcnt(0)" ::: "memory");   // last tile
        }
        __builtin_amdgcn_s_barrier();                          // publish buf t
        __builtin_amdgcn_sched_barrier(0);
        compute(t & 1);
        __builtin_amdgcn_sched_barrier(0);
        asm volatile("" ::: "memory");
        __builtin_amdgcn_s_barrier();                          // reads done before overwrite
    }

    // bf16 slab: [qd][t2][lane][4] shorts + ksum tail (e-order)
    unsigned short* slab = partial + ((size_t)((bb * 16 + hq * 4 + hh) * CHUNKS + ch)) * 4160;
#pragma unroll
    for (int mi = 0; mi < 2; ++mi)
#pragma unroll
        for (int ni = 0; ni < 2; ++ni) {
            uint2 w;
            w.x = cvt_pk_bf16(acc[mi][ni][0], acc[mi][ni][1]);
            w.y = cvt_pk_bf16(acc[mi][ni][2], acc[mi][ni][3]);
            *(uint2*)&slab[qd * 1024 + (mi * 2 + ni) * 256 + lane * 4] = w;
        }
    if (dh == 0 && r == 0) {
#pragma unroll
        for (int mi = 0; mi < 2; ++mi) {
            uint2 w;
            w.x = cvt_pk_bf16(accs[mi][0], accs[mi][1]);
            w.y = cvt_pk_bf16(accs[mi][2], accs[mi][3]);
            *(uint2*)&slab[4096 + 32 * eh + 16 * mi + 4 * g] = w;
        }
    }
}

// ---------------------------------------------------------------------------
// Kernel A2: sum 16 bf16 chunk blobs -> TRANSPOSED bf16 context (frag-ready).
// CT[d][e] = bf16(ctx[e][d]); CT[64][e] = bf16(ksum[e]). grid = 256.
// ---------------------------------------------------------------------------
__global__ __launch_bounds__(256) void ctx_reduce(const unsigned short* __restrict__ partial,
                                                  unsigned short* __restrict__ ctxbf) {
    const int head = blockIdx.x >> 2, part = blockIdx.x & 3;
    const unsigned short* pbase = partial + (size_t)head * CHUNKS * 4160;
    unsigned short* cbase = ctxbf + (size_t)head * 4160;
    const int lo = part * 260;
    for (int i4 = lo + threadIdx.x; i4 < lo + 260; i4 += 256) {
        float s[4] = {0.f, 0.f, 0.f, 0.f};
#pragma unroll
        for (int c = 0; c < CHUNKS; ++c) {
            const ushort4 v = *(const ushort4*)&pbase[(size_t)c * 4160 + i4 * 4];
            s[0] += bf2f(v.x); s[1] += bf2f(v.y);
            s[2] += bf2f(v.z); s[3] += bf2f(v.w);
        }
        const int f0 = i4 * 4;
        if (f0 < 4096) {
#pragma unroll
            for (int k = 0; k < 4; ++k) {
                const int f = f0 + k;
                const int qd = f >> 10, t2 = (f >> 8) & 3, ln = (f >> 2) & 63, q = f & 3;
                const int e = 32 * (qd >> 1) + 16 * (t2 >> 1) + 4 * (ln >> 4) + q;
                const int d = 32 * (qd & 1) + 16 * (t2 & 1) + (ln & 15);
                cbase[d * 64 + e] = (unsigned short)f2bf(s[k]);
            }
        } else {
#pragma unroll
            for (int k = 0; k < 4; ++k) cbase[f0 + k] = (unsigned short)f2bf(s[k]);
        }
    }
}

// ---------------------------------------------------------------------------
// Kernel B: out = (Q' ctx) / (Q' ksum + eps) via MFMA. (R8-verbatim, proven:
// barrier-free, 4 blocks/CU, TLP self-overlap. grid = 1024, block = 256.)
// ---------------------------------------------------------------------------
__global__ __launch_bounds__(256, 4) void attn_out(const float* __restrict__ Q,
                                                   const unsigned short* __restrict__ ctxbf,
                                                   float* __restrict__ out) {
    const int head = blockIdx.x >> 4, nb = blockIdx.x & 15;
    const int b = head >> 4, h = head & 15;
    const int tid = threadIdx.x, wave = tid >> 6, lane = tid & 63;
    const int g = lane >> 4, r = lane & 15;
    const unsigned short* C = ctxbf + (size_t)head * 4160;

    bf16x8 bfr[2][5];
#pragma unroll
    for (int kt = 0; kt < 2; ++kt) {
#pragma unroll
        for (int n = 0; n < 4; ++n)
            bfr[kt][n] = *(const bf16x8*)&C[(16 * n + r) * 64 + kt * 32 + 8 * g];
        bf16x8 ks = *(const bf16x8*)&C[4096 + kt * 32 + 8 * g];
        if (r != 0) {
#pragma unroll
            for (int j = 0; j < 8; ++j) ks[j] = 0;
        }
        bfr[kt][4] = ks;
    }

    const int n0 = nb * 256 + wave * 64;
    const float* qbase = Q + ((size_t)b * T_SEQ + n0) * D_MODEL + (size_t)h * 64;

    f32x4 acc[4][5];
#pragma unroll
    for (int m = 0; m < 4; ++m)
#pragma unroll
        for (int n = 0; n < 5; ++n)
#pragma unroll
            for (int q = 0; q < 4; ++q) acc[m][n][q] = 0.f;

    union U8 { unsigned u[4]; bf16x8 v; };
#pragma unroll
    for (int kt = 0; kt < 2; ++kt)
#pragma unroll
        for (int m = 0; m < 4; ++m) {
            const float* qp = qbase + (size_t)(16 * m + r) * D_MODEL + kt * 32 + 8 * g;
            const float4 q1 = *(const float4*)qp;
            const float4 q2 = *(const float4*)(qp + 4);
            U8 a;
            a.u[0] = cvt_pk_bf16(elu1(q1.x), elu1(q1.y));
            a.u[1] = cvt_pk_bf16(elu1(q1.z), elu1(q1.w));
            a.u[2] = cvt_pk_bf16(elu1(q2.x), elu1(q2.y));
            a.u[3] = cvt_pk_bf16(elu1(q2.z), elu1(q2.w));
#pragma unroll
            for (int n = 0; n < 5; ++n)
                acc[m][n] = __builtin_amdgcn_mfma_f32_16x16x32_bf16(a.v, bfr[kt][n], acc[m][n], 0, 0, 0);
        }

#pragma unroll
    for (int m = 0; m < 4; ++m) {
        float dinv[4];
#pragma unroll
        for (int q = 0; q < 4; ++q)
            dinv[q] = 1.f / (__shfl(acc[m][4][q], lane & 48) + EPS);
#pragma unroll
        for (int q = 0; q < 4; ++q) {
            float* op = out + ((size_t)b * T_SEQ + n0 + 16 * m + 4 * g + q) * D_MODEL
                        + (size_t)h * 64 + r;
#pragma unroll
            for (int n = 0; n < 4; ++n) op[16 * n] = acc[m][n][q] * dinv[q];
        }
    }
}

extern "C" void kernel_launch(void* const* d_in, const int* in_sizes, int n_in,
                              void* d_out, int out_size, void* d_ws, size_t ws_size,
                              hipStream_t stream) {
    const float* Q = (const float*)d_in[0];
    const float* K = (const float*)d_in[1];
    const float* V = (const float*)d_in[2];
    float* out = (float*)d_out;

    // Partials (1024 slabs * 4160 bf16 = 8.5 MB) live in d_out-as-scratch;
    // consumed by ctx_reduce, then d_out is fully overwritten by attn_out.
    unsigned short* partial = (unsigned short*)d_out;
    unsigned short* ctxbf   = (unsigned short*)d_ws;   // 64*4160 shorts (~0.5 MB)

    hipLaunchKernelGGL(ctx_fused,  dim3(256),  dim3(1024), 0, stream, K, V, partial);
    hipLaunchKernelGGL(ctx_reduce, dim3(256),  dim3(256),  0, stream, partial, ctxbf);
    hipLaunchKernelGGL(attn_out,   dim3(1024), dim3(256),  0, stream, Q, ctxbf, out);
}